// Round 3
// baseline (204.788 us; speedup 1.0000x reference)
//
#include <hip/hip_runtime.h>
#include <hip/hip_bf16.h>

// Problem constants
#define NN   4096      // nodes
#define FIN  1433      // input features
#define KPAD 1536      // padded K for GEMM1 (24 * 64)
#define NH   8         // heads
#define ND   64        // hidden per head
#define CD   512       // NH*ND

typedef float f32x4 __attribute__((ext_vector_type(4)));
typedef short s16x8 __attribute__((ext_vector_type(8)));   // 8 bf16 (guide-verified operand type)

#define MFMA16(a, b, c) __builtin_amdgcn_mfma_f32_16x16x32_bf16((a), (b), (c), 0, 0, 0)

__device__ __forceinline__ void gload_lds16(const void* g, void* l) {
  __builtin_amdgcn_global_load_lds((const __attribute__((address_space(1))) void*)g,
                                   (__attribute__((address_space(3))) void*)l, 16, 0, 0);
}

__device__ __forceinline__ ushort f2bf(float x) {
  __hip_bfloat16 b = __float2bfloat16(x);
  ushort u;
  __builtin_memcpy(&u, &b, 2);
  return u;
}

// ---------------------------------------------------------------------------
// Kernel 1: f32 -> bf16 cast with K padding (1433 -> 1536, zero fill).
// Vectorized per G13: 8 elems/thread, one 16B store. kout%8==0 so a group
// never crosses a row; dst byte offset = (r*kout+k0)*2 is 16B-aligned.
// Src reads stay scalar dword (row base only 4B-aligned: 1433 odd).
// ---------------------------------------------------------------------------
__global__ void castpad_kernel(const float* __restrict__ src, ushort* __restrict__ dst,
                               int rows, int kin, int kout) {
  int i = blockIdx.x * blockDim.x + threadIdx.x;   // one 8-elem group
  int kg = kout >> 3;
  int total = rows * kg;
  if (i >= total) return;
  int r  = i / kg;
  int k0 = (i - r * kg) << 3;
  s16x8 v;
#pragma unroll
  for (int j = 0; j < 8; ++j) {
    int k = k0 + j;
    float f = (k < kin) ? src[(size_t)r * kin + k] : 0.0f;
    v[j] = (short)f2bf(f);
  }
  *reinterpret_cast<s16x8*>(&dst[(size_t)r * kout + k0]) = v;
}

// ---------------------------------------------------------------------------
// Kernel 2: GEMM1  g = vertex @ W_vert^T   (NT, both K-contiguous)
// A: [NN][KPAD] bf16, B: [CD][KPAD] bf16, out G: [NN][CD] bf16
// 64x64 tile, 4 waves (2x2 of 32x32 wave tiles), BK=64,
// DOUBLE-BUFFERED 2-phase prefetch (T3-minimum): stage(next) || compute(cur),
// one barrier per K-step. global_load_lds width 16, chunk-XOR swizzle
// (linear LDS dest + pre-swizzled global source + swizzled ds_read — G21).
// ---------------------------------------------------------------------------
__global__ __launch_bounds__(256, 4) void gemm1_kernel(const ushort* __restrict__ A,
                                                       const ushort* __restrict__ B,
                                                       ushort* __restrict__ G) {
  __shared__ ushort As[2][64][64];
  __shared__ ushort Bs[2][64][64];
  const int tid  = threadIdx.x;
  const int lane = tid & 63;
  const int w    = tid >> 6;       // wave 0..3
  const int wr   = w >> 1, wc = w & 1;
  const int row0 = blockIdx.y * 64;   // over NN
  const int col0 = blockIdx.x * 64;   // over CD

  f32x4 acc[2][2] = {};

  auto stage = [&](int buf, int k0) {
#pragma unroll
    for (int c = 0; c < 2; ++c) {
      int ci = (w * 2 + c) * 64 + lane;     // 16B-chunk index 0..511
      int r  = ci >> 3;                     // LDS row 0..63
      int cp = ci & 7;                      // chunk pos within row
      int gc = cp ^ (r & 7);                // global chunk to fetch (involution)
      gload_lds16(A + (size_t)(row0 + r) * KPAD + k0 + gc * 8,
                  &As[buf][0][0] + (size_t)(w * 2 + c) * 512);
      gload_lds16(B + (size_t)(col0 + r) * KPAD + k0 + gc * 8,
                  &Bs[buf][0][0] + (size_t)(w * 2 + c) * 512);
    }
  };

  stage(0, 0);
  __syncthreads();          // compiler drains vmcnt(0) before s_barrier
  int cur = 0;

  for (int k0 = 0; k0 < KPAD; k0 += 64) {
    if (k0 + 64 < KPAD) stage(cur ^ 1, k0 + 64);   // prefetch next K-tile
#pragma unroll
    for (int kk = 0; kk < 64; kk += 32) {
      int kq = (kk >> 3) + (lane >> 4);     // chunk index of this lane's 8 bf16
      s16x8 af[2], bfv[2];
#pragma unroll
      for (int f = 0; f < 2; ++f) {
        int ar = wr * 32 + f * 16 + (lane & 15);
        af[f]  = *reinterpret_cast<const s16x8*>(&As[cur][ar][(kq ^ (ar & 7)) * 8]);
        int br = wc * 32 + f * 16 + (lane & 15);
        bfv[f] = *reinterpret_cast<const s16x8*>(&Bs[cur][br][(kq ^ (br & 7)) * 8]);
      }
#pragma unroll
      for (int fi = 0; fi < 2; ++fi)
#pragma unroll
        for (int fj = 0; fj < 2; ++fj)
          acc[fi][fj] = MFMA16(af[fi], bfv[fj], acc[fi][fj]);
    }
    __syncthreads();        // joins waves + drains prefetch DMA writes
    cur ^= 1;
  }

  // epilogue: C/D layout col=lane&15, row=(lane>>4)*4+reg  [m89-verified]
#pragma unroll
  for (int fi = 0; fi < 2; ++fi)
#pragma unroll
    for (int fj = 0; fj < 2; ++fj)
#pragma unroll
      for (int r = 0; r < 4; ++r) {
        int gr = row0 + wr * 32 + fi * 16 + (lane >> 4) * 4 + r;
        int gcol = col0 + wc * 32 + fj * 16 + (lane & 15);
        G[(size_t)gr * CD + gcol] = f2bf(acc[fi][fj][r]);
      }
}

// ---------------------------------------------------------------------------
// Kernel 3: fused per-head Gram + head-mix + leaky-relu + head-sum.
// Upper-triangle 64x64 tiles only (output is symmetric); mirror via LDS
// transpose. 4 waves, wave tile 32x32, 8 separate per-head accumulators
// (128 acc VGPRs — nonlinearity between gram and sum forces per-head accs,
// which caps the wave tile at 32x32). DOUBLE-BUFFERED 2-phase prefetch
// across the 8 head-tiles, one barrier per head.
// ---------------------------------------------------------------------------
__global__ __launch_bounds__(256, 2) void gram_kernel(const ushort* __restrict__ G,
                                                      const float* __restrict__ Wattn,
                                                      float* __restrict__ out) {
  const int bi = blockIdx.y;   // row tile
  const int bj = blockIdx.x;   // col tile
  if (bj < bi) return;         // symmetric: only upper triangle (uniform exit)

  __shared__ union LdsU {
    struct { ushort A[2][64][64]; ushort B[2][64][64]; } s;  // 32 KB staging
    float t[64][65];           // +1 pad: transpose staging (reuses dead bufs)
  } lds;
  __shared__ float sW[8][8];

  const int tid  = threadIdx.x;
  const int lane = tid & 63;
  const int w    = tid >> 6;
  const int wr   = w >> 1, wc = w & 1;
  const int ri0  = bi * 64, ci0 = bj * 64;

  if (tid < 64) sW[tid >> 3][tid & 7] = Wattn[tid];

  f32x4 acc[8][2][2] = {};   // [head][fi][fj] — h-loop fully unrolled (static idx)

  auto stage = [&](int buf, int h) {
#pragma unroll
    for (int c = 0; c < 2; ++c) {
      int ci = (w * 2 + c) * 64 + lane;
      int r  = ci >> 3;
      int cp = ci & 7;
      int gc = cp ^ (r & 7);
      gload_lds16(G + (size_t)(ri0 + r) * CD + h * 64 + gc * 8,
                  &lds.s.A[buf][0][0] + (size_t)(w * 2 + c) * 512);
      gload_lds16(G + (size_t)(ci0 + r) * CD + h * 64 + gc * 8,
                  &lds.s.B[buf][0][0] + (size_t)(w * 2 + c) * 512);
    }
  };

  stage(0, 0);
  __syncthreads();
  int cur = 0;

#pragma unroll
  for (int h = 0; h < 8; ++h) {
    if (h + 1 < 8) stage(cur ^ 1, h + 1);   // prefetch next head's tiles
#pragma unroll
    for (int kk = 0; kk < 64; kk += 32) {
      int kq = (kk >> 3) + (lane >> 4);
      s16x8 af[2], bfv[2];
#pragma unroll
      for (int f = 0; f < 2; ++f) {
        int ar = wr * 32 + f * 16 + (lane & 15);
        af[f]  = *reinterpret_cast<const s16x8*>(&lds.s.A[cur][ar][(kq ^ (ar & 7)) * 8]);
        int br = wc * 32 + f * 16 + (lane & 15);
        bfv[f] = *reinterpret_cast<const s16x8*>(&lds.s.B[cur][br][(kq ^ (br & 7)) * 8]);
      }
#pragma unroll
      for (int fi = 0; fi < 2; ++fi)
#pragma unroll
        for (int fj = 0; fj < 2; ++fj)
          acc[h][fi][fj] = MFMA16(af[fi], bfv[fj], acc[h][fi][fj]);
    }
    __syncthreads();
    cur ^= 1;
  }

  // Epilogue: z_g = sum_h gram_h * W[g][h];  out = sum_g lrelu(z_g)
  // Loop g outer / h inner: 1 LDS broadcast read per (g,h), 16 FMAs on regs.
  float o[2][2][4] = {};
#pragma unroll
  for (int g = 0; g < 8; ++g) {
    float z[2][2][4] = {};
#pragma unroll
    for (int h = 0; h < 8; ++h) {
      float wgh = sW[g][h];
#pragma unroll
      for (int fi = 0; fi < 2; ++fi)
#pragma unroll
        for (int fj = 0; fj < 2; ++fj)
#pragma unroll
          for (int r = 0; r < 4; ++r)
            z[fi][fj][r] = fmaf(acc[h][fi][fj][r], wgh, z[fi][fj][r]);
    }
#pragma unroll
    for (int fi = 0; fi < 2; ++fi)
#pragma unroll
      for (int fj = 0; fj < 2; ++fj)
#pragma unroll
        for (int r = 0; r < 4; ++r) {
          float zz = z[fi][fj][r];
          o[fi][fj][r] += fmaxf(zz, 0.2f * zz);   // leaky relu, slope 0.2
        }
  }

  // direct write of (bi,bj) tile — 16 consecutive lanes = 64B contiguous
#pragma unroll
  for (int fi = 0; fi < 2; ++fi)
#pragma unroll
    for (int fj = 0; fj < 2; ++fj)
#pragma unroll
      for (int r = 0; r < 4; ++r) {
        int rr = wr * 32 + fi * 16 + (lane >> 4) * 4 + r;
        int cc = wc * 32 + fj * 16 + (lane & 15);
        out[(size_t)(ri0 + rr) * NN + ci0 + cc] = o[fi][fj][r];
      }

  // mirrored write of (bj,bi) tile via LDS transpose (skip diagonal)
  if (bi != bj) {
    __syncthreads();   // staging buffers dead; reuse as f32 [64][65]
#pragma unroll
    for (int fi = 0; fi < 2; ++fi)
#pragma unroll
      for (int fj = 0; fj < 2; ++fj)
#pragma unroll
        for (int r = 0; r < 4; ++r) {
          int rr = wr * 32 + fi * 16 + (lane >> 4) * 4 + r;
          int cc = wc * 32 + fj * 16 + (lane & 15);
          lds.t[cc][rr] = o[fi][fj][r];   // t[c][r] = V(r,c)
        }
    __syncthreads();
    int a  = tid >> 2;          // transposed-tile row 0..63
    int cb = (tid & 3) * 16;    // 16-float chunk
#pragma unroll
    for (int jj = 0; jj < 4; ++jj) {
      float4 v;
      v.x = lds.t[a][cb + jj * 4 + 0];
      v.y = lds.t[a][cb + jj * 4 + 1];
      v.z = lds.t[a][cb + jj * 4 + 2];
      v.w = lds.t[a][cb + jj * 4 + 3];
      *reinterpret_cast<float4*>(&out[(size_t)(ci0 + a) * NN + ri0 + cb + jj * 4]) = v;
    }
  }
}

// ---------------------------------------------------------------------------
extern "C" void kernel_launch(void* const* d_in, const int* in_sizes, int n_in,
                              void* d_out, int out_size, void* d_ws, size_t ws_size,
                              hipStream_t stream) {
  const float* vertex = (const float*)d_in[0];   // [4096][1433] f32
  const float* Wvert  = (const float*)d_in[1];   // [512][1433]  f32
  const float* Wattn  = (const float*)d_in[2];   // [8][8]       f32
  float* out = (float*)d_out;                    // [4096][4096] f32

  char* ws = (char*)d_ws;
  ushort* Va = (ushort*)ws;                                           // [4096][1536] bf16
  ushort* Wb = (ushort*)(ws + (size_t)NN * KPAD * 2);                 // [512][1536]  bf16
  ushort* G  = (ushort*)(ws + (size_t)NN * KPAD * 2 + (size_t)CD * KPAD * 2); // [4096][512] bf16

  int tot1 = NN * (KPAD / 8);
  castpad_kernel<<<(tot1 + 255) / 256, 256, 0, stream>>>(vertex, Va, NN, FIN, KPAD);
  int tot2 = CD * (KPAD / 8);
  castpad_kernel<<<(tot2 + 255) / 256, 256, 0, stream>>>(Wvert, Wb, CD, FIN, KPAD);

  gemm1_kernel<<<dim3(CD / 64, NN / 64), 256, 0, stream>>>(Va, Wb, G);

  gram_kernel<<<dim3(NN / 64, NN / 64), 256, 0, stream>>>(G, Wattn, out);
}

// Round 6
// 193.089 us; speedup vs baseline: 1.0606x; 1.0606x over previous
//
#include <hip/hip_runtime.h>
#include <hip/hip_bf16.h>

// Problem constants
#define NN   4096      // nodes
#define FIN  1433      // input features
#define KPAD 1536      // padded K for GEMM1 (12 * 128)
#define NH   8         // heads
#define ND   64        // hidden per head
#define CD   512       // NH*ND

typedef float f32x4 __attribute__((ext_vector_type(4)));
typedef short s16x8 __attribute__((ext_vector_type(8)));   // 8 bf16

#define MFMA16(a, b, c) __builtin_amdgcn_mfma_f32_16x16x32_bf16((a), (b), (c), 0, 0, 0)

__device__ __forceinline__ void gload_lds16(const void* g, void* l) {
  __builtin_amdgcn_global_load_lds((const __attribute__((address_space(1))) void*)g,
                                   (__attribute__((address_space(3))) void*)l, 16, 0, 0);
}

__device__ __forceinline__ ushort f2bf(float x) {
  __hip_bfloat16 b = __float2bfloat16(x);
  ushort u;
  __builtin_memcpy(&u, &b, 2);
  return u;
}

// ---------------------------------------------------------------------------
// Kernel 1: f32 -> bf16 cast with K padding (1433 -> 1536, zero fill).
// 8 elems/thread, one 16B store (G13). Verified working (round 3).
// ---------------------------------------------------------------------------
__global__ void castpad_kernel(const float* __restrict__ src, ushort* __restrict__ dst,
                               int rows, int kin, int kout) {
  int i = blockIdx.x * blockDim.x + threadIdx.x;   // one 8-elem group
  int kg = kout >> 3;
  int total = rows * kg;
  if (i >= total) return;
  int r  = i / kg;
  int k0 = (i - r * kg) << 3;
  s16x8 v;
#pragma unroll
  for (int j = 0; j < 8; ++j) {
    int k = k0 + j;
    float f = (k < kin) ? src[(size_t)r * kin + k] : 0.0f;
    v[j] = (short)f2bf(f);
  }
  *reinterpret_cast<s16x8*>(&dst[(size_t)r * kout + k0]) = v;
}

// ---------------------------------------------------------------------------
// Kernel 2: GEMM1  g = vertex @ W_vert^T   (NT, both K-contiguous)
// A: [NN][KPAD] bf16, B: [CD][KPAD] bf16, out G: [NN][CD] bf16
// 64x64 tile, 4 waves, BK=128: 12 K-iters, 4x the DMA in flight per stage
// — amortizes the vmcnt(0)-before-barrier drain that made the 24-iter
// loop latency-bound (round-3 counters). Double-buffered, 64 KB LDS.
// ---------------------------------------------------------------------------
__global__ __launch_bounds__(256, 2) void gemm1_kernel(const ushort* __restrict__ A,
                                                       const ushort* __restrict__ B,
                                                       ushort* __restrict__ G) {
  __shared__ ushort As[2][64][128];   // 16 KB per buf
  __shared__ ushort Bs[2][64][128];
  const int tid  = threadIdx.x;
  const int lane = tid & 63;
  const int w    = tid >> 6;       // wave 0..3
  const int wr   = w >> 1, wc = w & 1;
  const int row0 = blockIdx.y * 64;   // over NN
  const int col0 = blockIdx.x * 64;   // over CD

  f32x4 acc[2][2] = {};

  // stage 64x128 bf16 per operand: 1024 16B-chunks, 4 instr/thread/operand.
  // chunk ci: r = ci>>4 (row), cp = ci&15; fetch global chunk cp^(r&7)
  // (involution, stays within row) so swizzled ds_read is conflict-spread.
  auto stage = [&](int buf, int k0) {
#pragma unroll
    for (int j = 0; j < 4; ++j) {
      int ci = (w * 4 + j) * 64 + lane;
      int r  = ci >> 4;
      int cp = ci & 15;
      int gc = cp ^ (r & 7);
      gload_lds16(A + (size_t)(row0 + r) * KPAD + k0 + gc * 8,
                  &As[buf][0][0] + (size_t)(w * 4 + j) * 512);
      gload_lds16(B + (size_t)(col0 + r) * KPAD + k0 + gc * 8,
                  &Bs[buf][0][0] + (size_t)(w * 4 + j) * 512);
    }
  };

  stage(0, 0);
  __syncthreads();
  int cur = 0;

  for (int k0 = 0; k0 < KPAD; k0 += 128) {
    if (k0 + 128 < KPAD) stage(cur ^ 1, k0 + 128);   // prefetch next K-tile
#pragma unroll
    for (int kk = 0; kk < 4; ++kk) {                 // 4 x K=32 sub-steps
      int kq = kk * 4 + (lane >> 4);                 // chunk 0..15 within row
      s16x8 af[2], bfv[2];
#pragma unroll
      for (int f = 0; f < 2; ++f) {
        int ar = wr * 32 + f * 16 + (lane & 15);
        af[f]  = *reinterpret_cast<const s16x8*>(&As[cur][ar][(kq ^ (ar & 7)) * 8]);
        int br = wc * 32 + f * 16 + (lane & 15);
        bfv[f] = *reinterpret_cast<const s16x8*>(&Bs[cur][br][(kq ^ (br & 7)) * 8]);
      }
#pragma unroll
      for (int fi = 0; fi < 2; ++fi)
#pragma unroll
        for (int fj = 0; fj < 2; ++fj)
          acc[fi][fj] = MFMA16(af[fi], bfv[fj], acc[fi][fj]);
    }
    __syncthreads();        // joins waves + drains prefetch DMA writes
    cur ^= 1;
  }

  // epilogue: C/D layout col=lane&15, row=(lane>>4)*4+reg  [m89-verified]
#pragma unroll
  for (int fi = 0; fi < 2; ++fi)
#pragma unroll
    for (int fj = 0; fj < 2; ++fj)
#pragma unroll
      for (int r = 0; r < 4; ++r) {
        int gr = row0 + wr * 32 + fi * 16 + (lane >> 4) * 4 + r;
        int gcol = col0 + wc * 32 + fj * 16 + (lane & 15);
        G[(size_t)gr * CD + gcol] = f2bf(acc[fi][fj][r]);
      }
}

// ---------------------------------------------------------------------------
// Kernel 3: fused per-head Gram + head-mix + leaky-relu + head-sum.
// Counter-driven v2: round-3 version was latency-bound (MfmaUtil 3.2%,
// Occ 15%) — 8 tiny 16KB stages/block each draining vmcnt(0) at the
// barrier. Now: stage 4 HEADS at once (2 x 32 KB passes, 16 DMA
// instr/thread in flight), 3 barriers instead of 9; 1-D grid of exactly
// the 2080 upper-triangle tiles (no no-op blocks) with bijective XCD
// chunk swizzle (2080 % 8 == 0) for row-band L2 locality.
// ---------------------------------------------------------------------------
__global__ __launch_bounds__(256, 2) void gram_kernel(const ushort* __restrict__ G,
                                                      const float* __restrict__ Wattn,
                                                      float* __restrict__ out) {
  // ---- triangular tile decode with XCD swizzle ----
  const int nwg = (NN / 64) * (NN / 64 + 1) / 2;   // 2080
  const int cpx = nwg / 8;                          // 260
  int b = blockIdx.x;
  int t = (b % 8) * cpx + (b / 8);                  // bijective: 2080 % 8 == 0
  // row bi = largest r with S(r) = (129r - r^2)/2 <= t
  int bi = (int)((129.0f - sqrtf(16641.0f - 8.0f * (float)t)) * 0.5f);
  while ((129 * (bi + 1) - (bi + 1) * (bi + 1)) / 2 <= t) ++bi;
  while ((129 * bi - bi * bi) / 2 > t) --bi;
  const int bj = bi + (t - (129 * bi - bi * bi) / 2);
  const int ri0 = bi * 64, ci0 = bj * 64;

  __shared__ union LdsU {
    struct { ushort A[64][256]; ushort B[64][256]; } s;  // 32 KB + 32 KB
    float t[64][65];           // +1 pad: transpose staging (reuses dead bufs)
  } lds;
  __shared__ float sW[8][8];

  const int tid  = threadIdx.x;
  const int lane = tid & 63;
  const int w    = tid >> 6;
  const int wr   = w >> 1, wc = w & 1;

  if (tid < 64) sW[tid >> 3][tid & 7] = Wattn[tid];

  f32x4 acc[8][2][2] = {};   // [head][fi][fj] — fully static indexing

  // stage heads 4p..4p+3: per operand 64 rows x 256 cols bf16 = 32 KB
  // = 2048 chunks of 16B; 8 instr/thread/operand. Row = 32 chunks;
  // fetch global chunk cp^(r&7) (stays within row; involution).
  auto stage = [&](int p) {
#pragma unroll
    for (int j = 0; j < 8; ++j) {
      int ci = (w * 8 + j) * 64 + lane;   // 0..2047
      int r  = ci >> 5;
      int cp = ci & 31;
      int gc = cp ^ (r & 7);
      gload_lds16(G + (size_t)(ri0 + r) * CD + p * 256 + gc * 8,
                  &lds.s.A[0][0] + (size_t)(w * 8 + j) * 512);
      gload_lds16(G + (size_t)(ci0 + r) * CD + p * 256 + gc * 8,
                  &lds.s.B[0][0] + (size_t)(w * 8 + j) * 512);
    }
  };

  // compute heads 4p..4p+3 from the staged pass
  auto compute = [&](int p) {
#pragma unroll
    for (int hh = 0; hh < 4; ++hh) {
#pragma unroll
      for (int kk = 0; kk < 2; ++kk) {
        int kq = kk * 4 + (lane >> 4);     // chunk 0..7 within head
        s16x8 af[2], bfv[2];
#pragma unroll
        for (int f = 0; f < 2; ++f) {
          int ar = wr * 32 + f * 16 + (lane & 15);
          af[f]  = *reinterpret_cast<const s16x8*>(
                     &lds.s.A[ar][((hh * 8 + kq) ^ (ar & 7)) * 8]);
          int br = wc * 32 + f * 16 + (lane & 15);
          bfv[f] = *reinterpret_cast<const s16x8*>(
                     &lds.s.B[br][((hh * 8 + kq) ^ (br & 7)) * 8]);
        }
        int h = p * 4 + hh;
#pragma unroll
        for (int fi = 0; fi < 2; ++fi)
#pragma unroll
          for (int fj = 0; fj < 2; ++fj)
            acc[h][fi][fj] = MFMA16(af[fi], bfv[fj], acc[h][fi][fj]);
      }
    }
  };

  stage(0);
  __syncthreads();          // drains DMA; pass-0 data ready
  compute(0);
  __syncthreads();          // all pass-0 reads done before overwrite
  stage(1);
  __syncthreads();          // pass-1 data ready
  compute(1);

  // Epilogue: z_g = sum_h gram_h * W[g][h];  out = sum_g lrelu(z_g)
  float o[2][2][4] = {};
#pragma unroll
  for (int g = 0; g < 8; ++g) {
    float z[2][2][4] = {};
#pragma unroll
    for (int h = 0; h < 8; ++h) {
      float wgh = sW[g][h];
#pragma unroll
      for (int fi = 0; fi < 2; ++fi)
#pragma unroll
        for (int fj = 0; fj < 2; ++fj)
#pragma unroll
          for (int r = 0; r < 4; ++r)
            z[fi][fj][r] = fmaf(acc[h][fi][fj][r], wgh, z[fi][fj][r]);
    }
#pragma unroll
    for (int fi = 0; fi < 2; ++fi)
#pragma unroll
      for (int fj = 0; fj < 2; ++fj)
#pragma unroll
        for (int r = 0; r < 4; ++r) {
          float zz = z[fi][fj][r];
          o[fi][fj][r] += fmaxf(zz, 0.2f * zz);   // leaky relu, slope 0.2
        }
  }

  // direct write of (bi,bj) tile — 16 consecutive lanes = 64B contiguous
#pragma unroll
  for (int fi = 0; fi < 2; ++fi)
#pragma unroll
    for (int fj = 0; fj < 2; ++fj)
#pragma unroll
      for (int r = 0; r < 4; ++r) {
        int rr = wr * 32 + fi * 16 + (lane >> 4) * 4 + r;
        int cc = wc * 32 + fj * 16 + (lane & 15);
        out[(size_t)(ri0 + rr) * NN + ci0 + cc] = o[fi][fj][r];
      }

  // mirrored write of (bj,bi) tile via LDS transpose (skip diagonal)
  if (bi != bj) {
    __syncthreads();   // staging buffers dead; reuse as f32 [64][65]
#pragma unroll
    for (int fi = 0; fi < 2; ++fi)
#pragma unroll
      for (int fj = 0; fj < 2; ++fj)
#pragma unroll
        for (int r = 0; r < 4; ++r) {
          int rr = wr * 32 + fi * 16 + (lane >> 4) * 4 + r;
          int cc = wc * 32 + fj * 16 + (lane & 15);
          lds.t[cc][rr] = o[fi][fj][r];   // t[c][r] = V(r,c)
        }
    __syncthreads();
    int a  = tid >> 2;          // transposed-tile row 0..63
    int cb = (tid & 3) * 16;    // 16-float chunk
#pragma unroll
    for (int jj = 0; jj < 4; ++jj) {
      float4 v;
      v.x = lds.t[a][cb + jj * 4 + 0];
      v.y = lds.t[a][cb + jj * 4 + 1];
      v.z = lds.t[a][cb + jj * 4 + 2];
      v.w = lds.t[a][cb + jj * 4 + 3];
      *reinterpret_cast<float4*>(&out[(size_t)(ci0 + a) * NN + ri0 + cb + jj * 4]) = v;
    }
  }
}

// ---------------------------------------------------------------------------
extern "C" void kernel_launch(void* const* d_in, const int* in_sizes, int n_in,
                              void* d_out, int out_size, void* d_ws, size_t ws_size,
                              hipStream_t stream) {
  const float* vertex = (const float*)d_in[0];   // [4096][1433] f32
  const float* Wvert  = (const float*)d_in[1];   // [512][1433]  f32
  const float* Wattn  = (const float*)d_in[2];   // [8][8]       f32
  float* out = (float*)d_out;                    // [4096][4096] f32

  char* ws = (char*)d_ws;
  ushort* Va = (ushort*)ws;                                           // [4096][1536] bf16
  ushort* Wb = (ushort*)(ws + (size_t)NN * KPAD * 2);                 // [512][1536]  bf16
  ushort* G  = (ushort*)(ws + (size_t)NN * KPAD * 2 + (size_t)CD * KPAD * 2); // [4096][512] bf16

  int tot1 = NN * (KPAD / 8);
  castpad_kernel<<<(tot1 + 255) / 256, 256, 0, stream>>>(vertex, Va, NN, FIN, KPAD);
  int tot2 = CD * (KPAD / 8);
  castpad_kernel<<<(tot2 + 255) / 256, 256, 0, stream>>>(Wvert, Wb, CD, FIN, KPAD);

  gemm1_kernel<<<dim3(CD / 64, NN / 64), 256, 0, stream>>>(Va, Wb, G);

  int ntri = (NN / 64) * (NN / 64 + 1) / 2;   // 2080
  gram_kernel<<<ntri, 256, 0, stream>>>(G, Wattn, out);
}